// Round 1
// 98.780 us; speedup vs baseline: 1.0022x; 1.0022x over previous
//
#include <hip/hip_runtime.h>
#include <math.h>

// Model_21775484190778: Gaussian-splat PDE step. N=1024, K=5 -> S=25600 samples.
// R6: LDS-pipe vectorization. Measured time = 2x39us harness poison fills (fixed)
//     + ~20us k_fused. k_fused's conv/lin1 phases were LDS-b32-bound:
//  - conv_w restaged with stride 76 (16B-aligned rows; 12r%32 bank starts cover
//    all 32 banks per 8 lanes -> conflict-free ds_read_b128)
//  - conv reads w + 4x simg as float4 (5 b128 per 4 c's vs 20 b32)
//  - lin1 reads h[g] as float4 (4 b128 per 4 j's vs 16 b32)
//  - emb sub-net moved into the reduce barrier-section (depends only on sparams)
//  fma accumulation order is bit-identical to R5 (absmax must not move).

namespace {

constexpr int NG = 1024;
constexpr int G  = 4;                                    // gaussians per block
constexpr float DXF = 2.0f / 31.0f;
constexpr float NHALF_LOG2E = -0.72134752044448170367f;  // -0.5 * log2(e)
constexpr float TWO_LOG2E   = 2.88539008177792681472f;   //  2.0 * log2(e)
constexpr float LOG2E       = 1.44269504088896340736f;
constexpr float QCUT        = 80.0f;                     // exp(-40) cutoff

__device__ __forceinline__ float fast_tanh(float x) {
  x = fminf(9.0f, fmaxf(-9.0f, x));
  float t = __builtin_amdgcn_exp2f(TWO_LOG2E * x);
  return (t - 1.0f) * __builtin_amdgcn_rcpf(t + 1.0f);
}

__global__ __launch_bounds__(512) void k_fused(
    const float* __restrict__ means, const float* __restrict__ uu,
    const float* __restrict__ scaling, const float* __restrict__ transform,
    const float* __restrict__ conv_w, const float* __restrict__ conv_b,
    const float* __restrict__ emb_w, const float* __restrict__ emb_b,
    const float* __restrict__ lin1_w, const float* __restrict__ lin1_b,
    const float* __restrict__ sol_w, const float* __restrict__ sol_b,
    const float* __restrict__ tr_w, const float* __restrict__ tr_b,
    const float* __restrict__ sc_w, const float* __restrict__ sc_b,
    const float* __restrict__ tf_w, const float* __restrict__ tf_b,
    float* __restrict__ out)
{
  __shared__ __align__(16) float scw[200 * 76];   // conv_w (m*50+o) x 76, 60.8 KB
  __shared__ __align__(16) float4 sgp[NG];        // survivors: mx, my, a, b (16 KB)
  __shared__ __align__(16) float2 sgq[NG];        // survivors: c, u         (8 KB)
  __shared__ int s_cnt;
  __shared__ float r_us[5][100];
  __shared__ float r_pde[5][100];
  __shared__ __align__(16) float simg[G][76];     // per-g [3][25], padded row
  __shared__ float sparams[G][6];                 // mx, my, u, s0, s1, t0
  __shared__ __align__(16) float h[G][320];
  __shared__ __align__(16) float h2[G][320];
  __shared__ float hpart[G][6][8];

  const int i0 = blockIdx.x * G;        // first gaussian of this block
  const int tid = threadIdx.x;

  // ---- stage conv_w into LDS, re-strided 75 -> 76 (coalesced float4 loads) ----
  {
    const float4* src = (const float4*)conv_w;
    for (int idx = tid; idx < 3750; idx += 512) {
      float4 v = src[idx];
      const int e = idx * 4;
      const int r = e / 75;
      const int c = e - r * 75;
      float vv[4] = {v.x, v.y, v.z, v.w};
#pragma unroll
      for (int t = 0; t < 4; ++t) {
        int rr = r, cc = c + t;
        if (cc >= 75) { rr += 1; cc -= 75; }
        scw[rr * 76 + cc] = vv[t];
      }
    }
  }
  if (tid == 0) s_cnt = 0;
  if (tid < G * 6) {
    const int g = tid / 6, f = tid - g * 6, ig = i0 + g;
    float v;
    if (f < 2)       v = means[2 * ig + f];
    else if (f == 2) v = uu[ig];
    else if (f < 5)  v = scaling[2 * ig + (f - 3)];
    else             v = transform[ig];
    sparams[g][f] = v;
  }
  __syncthreads();

  // ---- union sample bbox of the G gaussians ----
  float lox = 1e30f, hix = -1e30f, loy = 1e30f, hiy = -1e30f;
#pragma unroll
  for (int g = 0; g < G; ++g) {
    lox = fminf(lox, sparams[g][0]); hix = fmaxf(hix, sparams[g][0]);
    loy = fminf(loy, sparams[g][1]); hiy = fmaxf(hiy, sparams[g][1]);
  }
  lox -= 2.0f * DXF; hix += 2.0f * DXF;
  loy -= 2.0f * DXF; hiy += 2.0f * DXF;

  // ---- cull + compact survivors ----
  const float2* means2 = (const float2*)means;
  const float2* scal2  = (const float2*)scaling;
  for (int g = tid; g < NG; g += 512) {
    float2 mg = means2[g];
    float2 sg = scal2[g];
    float t0 = transform[g];
    float ex = fmaxf(fmaxf(lox - mg.x, mg.x - hix), 0.0f);
    float ey = fmaxf(fmaxf(loy - mg.y, mg.y - hiy), 0.0f);
    float tr = sg.x * sg.x + sg.y * sg.y + t0 * t0;
    if (ex * ex + ey * ey <= QCUT * tr) {
      int idx = atomicAdd(&s_cnt, 1);
      // conic of L=[[s0,0],[t0,s1]]: a=(t0^2+s1^2)/(s0^2 s1^2), b=-t0/(s0 s1^2), c=1/s1^2
      float cc  = 1.0f / (sg.y * sg.y);
      float is0 = 1.0f / sg.x;
      float bb  = -t0 * cc * is0;
      float aa  = (t0 * t0 * cc + 1.0f) * is0 * is0;
      sgp[idx] = make_float4(mg.x, mg.y, aa, bb);
      sgq[idx] = make_float2(cc, uu[g]);
    }
  }
  __syncthreads();

  // ---- evaluate G*25 = 100 samples x cnt survivors (5 chunks) ----
  const int cnt = s_cnt;
  if (tid < 500) {
    const int c = tid / 100;              // chunk 0..4
    const int s = tid - c * 100;          // sample 0..99 (g = s/25, k = s%25)
    const int g = s / 25, k = s - g * 25;
    const int kx = k / 5, ky = k - kx * 5;
    const float sx = sparams[g][0] + (float)(kx - 2) * DXF;
    const float sy = sparams[g][1] + (float)(ky - 2) * DXF;
    float us = 0.0f, pde = 0.0f;
    for (int j = c; j < cnt; j += 5) {
      float4 p  = sgp[j];
      float2 qv = sgq[j];
      float dx = sx - p.x, dy = sy - p.y;
      float a = p.z, b = p.w, cc = qv.x;
      float Cd0 = a * dx + b * dy;
      float Cd1 = b * dx + cc * dy;
      float q   = dx * Cd0 + dy * Cd1;
      float w   = qv.y * __builtin_amdgcn_exp2f(NHALF_LOG2E * q);
      us  += w;
      pde += w * (Cd0 * Cd0 + Cd1 * Cd1 - (a + cc));
    }
    r_us[c][s]  = us;
    r_pde[c][s] = pde;
  }
  __syncthreads();

  // ---- reduce 5 chunks -> simg; emb sub-net overlapped here (needs only sparams) ----
  if (tid < 100) {
    const int g = tid / 25, k = tid - g * 25;
    float U = 0.0f, P = 0.0f;
#pragma unroll
    for (int c = 0; c < 5; ++c) { U += r_us[c][tid]; P += r_pde[c][tid]; }
    const int kx = k / 5, ky = k - kx * 5;
    const float sx = sparams[g][0] + (float)(kx - 2) * DXF;
    const float sy = sparams[g][1] + (float)(ky - 2) * DXF;
    simg[g][k]      = U;
    simg[g][25 + k] = P;
    simg[g][50 + k] = (fabsf(sx) < 1.0f && fabsf(sy) < 1.0f) ? 1.0f : 0.0f;
  }
  // emb: threads 200..319 -> (m,q) of 4x30 (independent of simg)
  if (tid >= 200 && tid < 320) {
    const int e = tid - 200;
    const int m = e / 30, q = e - m * 30;
    const float bb = emb_b[m * 30 + q];
    float acc[G] = {bb, bb, bb, bb};
#pragma unroll
    for (int p = 0; p < 6; ++p) {
      float wv = emb_w[(m * 6 + p) * 30 + q];
#pragma unroll
      for (int g = 0; g < G; ++g) acc[g] = fmaf(sparams[g][p], wv, acc[g]);
    }
#pragma unroll
    for (int g = 0; g < G; ++g) h[g][m * 80 + 50 + q] = fast_tanh(acc[g]);
  }
  __syncthreads();

  // ---- conv: 200 threads -> (m,o); all-b128 LDS reads, fma order = R5 ----
  if (tid < 200) {
    const int m = tid / 50, o = tid - m * 50;
    const float* w = scw + tid * 76;     // row (m*50+o) == tid
    const float bb = conv_b[tid];
    float a0 = bb, a1 = bb, a2 = bb, a3 = bb;
    const float4* w4 = (const float4*)w;
#pragma unroll
    for (int c4 = 0; c4 < 18; ++c4) {    // c = 0..71
      const float4 wv = w4[c4];
      const float4 i0 = *(const float4*)(simg[0] + c4 * 4);
      const float4 i1 = *(const float4*)(simg[1] + c4 * 4);
      const float4 i2 = *(const float4*)(simg[2] + c4 * 4);
      const float4 i3 = *(const float4*)(simg[3] + c4 * 4);
      a0 = fmaf(i0.x, wv.x, a0); a1 = fmaf(i1.x, wv.x, a1);
      a2 = fmaf(i2.x, wv.x, a2); a3 = fmaf(i3.x, wv.x, a3);
      a0 = fmaf(i0.y, wv.y, a0); a1 = fmaf(i1.y, wv.y, a1);
      a2 = fmaf(i2.y, wv.y, a2); a3 = fmaf(i3.y, wv.y, a3);
      a0 = fmaf(i0.z, wv.z, a0); a1 = fmaf(i1.z, wv.z, a1);
      a2 = fmaf(i2.z, wv.z, a2); a3 = fmaf(i3.z, wv.z, a3);
      a0 = fmaf(i0.w, wv.w, a0); a1 = fmaf(i1.w, wv.w, a1);
      a2 = fmaf(i2.w, wv.w, a2); a3 = fmaf(i3.w, wv.w, a3);
    }
#pragma unroll
    for (int c = 72; c < 75; ++c) {      // tail
      const float wv = w[c];
      a0 = fmaf(simg[0][c], wv, a0); a1 = fmaf(simg[1][c], wv, a1);
      a2 = fmaf(simg[2][c], wv, a2); a3 = fmaf(simg[3][c], wv, a3);
    }
    h[0][m * 80 + o] = fast_tanh(a0); h[1][m * 80 + o] = fast_tanh(a1);
    h[2][m * 80 + o] = fast_tanh(a2); h[3][m * 80 + o] = fast_tanh(a3);
  }
  __syncthreads();

  // ---- lin1: 320 threads -> (m,q); b128 LDS reads of h, fma order = R5 ----
  if (tid < 320) {
    const int m = tid / 80, q = tid - m * 80;
    const float* lw = lin1_w + m * 6400 + q;
    const float bb = lin1_b[m * 80 + q];
    float a0 = bb, a1 = bb, a2 = bb, a3 = bb;
#pragma unroll 5
    for (int j4 = 0; j4 < 20; ++j4) {
      const int j = j4 * 4;
      const float4 v0 = *(const float4*)(h[0] + m * 80 + j);
      const float4 v1 = *(const float4*)(h[1] + m * 80 + j);
      const float4 v2 = *(const float4*)(h[2] + m * 80 + j);
      const float4 v3 = *(const float4*)(h[3] + m * 80 + j);
      const float w0 = lw[(j + 0) * 80];
      const float w1 = lw[(j + 1) * 80];
      const float w2 = lw[(j + 2) * 80];
      const float w3 = lw[(j + 3) * 80];
      a0 = fmaf(v0.x, w0, a0); a1 = fmaf(v1.x, w0, a1);
      a2 = fmaf(v2.x, w0, a2); a3 = fmaf(v3.x, w0, a3);
      a0 = fmaf(v0.y, w1, a0); a1 = fmaf(v1.y, w1, a1);
      a2 = fmaf(v2.y, w1, a2); a3 = fmaf(v3.y, w1, a3);
      a0 = fmaf(v0.z, w2, a0); a1 = fmaf(v1.z, w2, a1);
      a2 = fmaf(v2.z, w2, a2); a3 = fmaf(v3.z, w2, a3);
      a0 = fmaf(v0.w, w3, a0); a1 = fmaf(v1.w, w3, a1);
      a2 = fmaf(v2.w, w3, a2); a3 = fmaf(v3.w, w3, a3);
    }
    h2[0][m * 80 + q] = fast_tanh(a0); h2[1][m * 80 + q] = fast_tanh(a1);
    h2[2][m * 80 + q] = fast_tanh(a2); h2[3][m * 80 + q] = fast_tanh(a3);
  }
  __syncthreads();

  // heads: 192 threads = g x 6 outputs x 8 chunks of 10
  if (tid < 192) {
    const int g = tid / 48, t = tid - g * 48;
    const int o = t >> 3, c8 = t & 7;
    const int m = (o == 0) ? 0 : (o < 3) ? 1 : (o < 5) ? 2 : 3;
    const float* wp; int stride;
    if (o == 0)      { wp = sol_w;            stride = 1; }
    else if (o < 3)  { wp = tr_w + (o - 1);   stride = 2; }
    else if (o < 5)  { wp = sc_w + (o - 3);   stride = 2; }
    else             { wp = tf_w;             stride = 1; }
    const float* hh = h2[g] + m * 80;
    float acc = 0.0f;
    const int j0 = c8 * 10;
#pragma unroll
    for (int j = 0; j < 10; ++j) acc = fmaf(hh[j0 + j], wp[(j0 + j) * stride], acc);
    hpart[g][o][c8] = acc;
  }
  __syncthreads();

  if (tid < G * 6) {
    const int g = tid / 6, o = tid - g * 6;
    float acc = 0.0f;
#pragma unroll
    for (int c = 0; c < 8; ++c) acc += hpart[g][o][c];
    float res;
    if (o == 0)      res = sparams[g][2] + acc + sol_b[0];
    else if (o < 3)  res = sparams[g][o - 1] + acc + tr_b[o - 1];
    else if (o < 5)  res = sparams[g][o] * __builtin_amdgcn_exp2f(LOG2E * (acc + sc_b[o - 3]));
    else             res = sparams[g][5] + acc + tf_b[0];
    out[(i0 + g) * 6 + o] = res;
  }
}

}  // namespace

extern "C" void kernel_launch(void* const* d_in, const int* in_sizes, int n_in,
                              void* d_out, int out_size, void* d_ws, size_t ws_size,
                              hipStream_t stream) {
  const float* means     = (const float*)d_in[0];
  const float* uu        = (const float*)d_in[1];
  const float* scaling   = (const float*)d_in[2];
  const float* transform = (const float*)d_in[3];
  const float* conv_w    = (const float*)d_in[4];
  const float* conv_b    = (const float*)d_in[5];
  const float* emb_w     = (const float*)d_in[6];
  const float* emb_b     = (const float*)d_in[7];
  const float* lin1_w    = (const float*)d_in[8];
  const float* lin1_b    = (const float*)d_in[9];
  const float* sol_w     = (const float*)d_in[10];
  const float* sol_b     = (const float*)d_in[11];
  const float* tr_w      = (const float*)d_in[12];
  const float* tr_b      = (const float*)d_in[13];
  const float* sc_w      = (const float*)d_in[14];
  const float* sc_b      = (const float*)d_in[15];
  const float* tf_w      = (const float*)d_in[16];
  const float* tf_b      = (const float*)d_in[17];

  float* out = (float*)d_out;

  k_fused<<<NG / G, 512, 0, stream>>>(means, uu, scaling, transform,
                                      conv_w, conv_b, emb_w, emb_b, lin1_w, lin1_b,
                                      sol_w, sol_b, tr_w, tr_b, sc_w, sc_b, tf_w, tf_b,
                                      out);
}